// Round 9
// baseline (4368.201 us; speedup 1.0000x reference)
//
#include <hip/hip_runtime.h>
#include <hip/hip_bf16.h>

#define BB 2
#define LL 2048
#define DD 1024
#define HH 16
#define DK 64
#define UU 40
#define BH (BB*HH)

typedef unsigned short u16;

__device__ inline float b2f_r9(u16 x) {
    union { unsigned short u; __hip_bfloat16 b; } c; c.u = x;
    return __bfloat162float(c.b);
}
// dual-dtype element load (fp32 or bf16 input), wave-uniform isF
__device__ inline float ldf_r9(const void* p, size_t i, int isF) {
    return isF ? ((const float*)p)[i] : b2f_r9(((const u16*)p)[i]);
}

// ---------------- K0: input dtype probe ----------------
__global__ __launch_bounds__(256) void detect_dtype_r9(const u16* __restrict__ q,
                                                       int* __restrict__ flag) {
    __shared__ float red[256];
    int tid = threadIdx.x;
    float mx = 0.f;
    for (int i = tid; i < 4096; i += 256) {
        float v = fabsf(b2f_r9(q[i]));
        if (!(v < 1e30f)) v = 1e38f;
        mx = fmaxf(mx, v);
    }
    red[tid] = mx; __syncthreads();
    for (int s = 128; s > 0; s >>= 1) {
        if (tid < s) red[tid] = fmaxf(red[tid], red[tid + s]);
        __syncthreads();
    }
    if (tid == 0) *flag = (red[0] > 1e20f) ? 1 : 0;
}

// ------------- K1: exact K projection, fp64 accum, hi/lo fp32 store -------------
__global__ __launch_bounds__(256) void kproj_exact_r9(
    const void* __restrict__ X, const void* __restrict__ W,
    const void* __restrict__ bias, float* __restrict__ Khi,
    float* __restrict__ Klo, const int* __restrict__ flag)
{
    __shared__ float sx[64 * 65];
    __shared__ float sw[64 * 65];
    int tid = threadIdx.x;
    int n0 = blockIdx.x * 64, f0 = blockIdx.y * 64;
    int isF = *flag;
    int ty = tid >> 4, tx = tid & 15;
    double acc[4][4] = {};
    for (int kc = 0; kc < 16; ++kc) {
        __syncthreads();
        for (int i = tid; i < 4096; i += 256) {
            int r = i >> 6, c = i & 63;
            sx[r * 65 + c] = ldf_r9(X, (size_t)(n0 + r) * DD + kc * 64 + c, isF);
            sw[r * 65 + c] = ldf_r9(W, (size_t)(f0 + r) * DD + kc * 64 + c, isF);
        }
        __syncthreads();
        for (int c = 0; c < 64; ++c) {
            double xa[4], wb[4];
#pragma unroll
            for (int a = 0; a < 4; ++a) xa[a] = (double)sx[(ty * 4 + a) * 65 + c];
#pragma unroll
            for (int q = 0; q < 4; ++q) wb[q] = (double)sw[(tx * 4 + q) * 65 + c];
#pragma unroll
            for (int a = 0; a < 4; ++a)
#pragma unroll
                for (int q = 0; q < 4; ++q) acc[a][q] += xa[a] * wb[q];
        }
    }
#pragma unroll
    for (int a = 0; a < 4; ++a) {
        int n = n0 + ty * 4 + a, b = n >> 11, l = n & (LL - 1);
#pragma unroll
        for (int q = 0; q < 4; ++q) {
            int f = f0 + tx * 4 + q, h = f >> 6, dk = f & 63;
            double v = acc[a][q] + (double)ldf_r9(bias, (size_t)f, isF);
            size_t o = ((size_t)(b * HH + h) * LL + l) * DK + dk;
            float hi = (float)v;
            Khi[o] = hi;
            Klo[o] = (float)(v - (double)hi);
        }
    }
}

// ---------------- K2: V projection, fp32 ----------------
__global__ __launch_bounds__(256) void proj_v_r9(
    const void* __restrict__ X, const void* __restrict__ W,
    const void* __restrict__ bias, float* __restrict__ out,
    const int* __restrict__ flag)
{
    __shared__ float sx[64 * 65];
    __shared__ float sw[64 * 65];
    int tid = threadIdx.x;
    int n0 = blockIdx.x * 64, f0 = blockIdx.y * 64;
    int isF = *flag;
    int ty = tid >> 4, tx = tid & 15;
    float acc[4][4] = {};
    for (int kc = 0; kc < 16; ++kc) {
        __syncthreads();
        for (int i = tid; i < 4096; i += 256) {
            int r = i >> 6, c = i & 63;
            sx[r * 65 + c] = ldf_r9(X, (size_t)(n0 + r) * DD + kc * 64 + c, isF);
            sw[r * 65 + c] = ldf_r9(W, (size_t)(f0 + r) * DD + kc * 64 + c, isF);
        }
        __syncthreads();
        for (int c = 0; c < 64; ++c) {
            float xa[4], wb[4];
#pragma unroll
            for (int a = 0; a < 4; ++a) xa[a] = sx[(ty * 4 + a) * 65 + c];
#pragma unroll
            for (int q = 0; q < 4; ++q) wb[q] = sw[(tx * 4 + q) * 65 + c];
#pragma unroll
            for (int a = 0; a < 4; ++a)
#pragma unroll
                for (int q = 0; q < 4; ++q) acc[a][q] = fmaf(xa[a], wb[q], acc[a][q]);
        }
    }
#pragma unroll
    for (int a = 0; a < 4; ++a) {
        int n = n0 + ty * 4 + a, b = n >> 11, l = n & (LL - 1);
#pragma unroll
        for (int q = 0; q < 4; ++q) {
            int f = f0 + tx * 4 + q, h = f >> 6, dk = f & 63;
            out[((size_t)(b * HH + h) * LL + l) * DK + dk] = acc[a][q] + ldf_r9(bias, (size_t)f, isF);
        }
    }
}

// ---- K3: register-tiled fused Q-proj (32 rows) + M = rowmax - rowmean (fp64) ----
// Phase 1: exact fp64 projection of 32 q-rows (thread: 8 rows x 1 outdim).
// Phase 2: QK^T with 2x2 register tile per thread over 32-key LDS chunks.
__global__ __launch_bounds__(256) void qk_stats_r9(
    const void* __restrict__ query, const void* __restrict__ Wq,
    const void* __restrict__ bq, const float* __restrict__ Khi,
    const float* __restrict__ Klo, double* __restrict__ Mv,
    const int* __restrict__ flag)
{
    __shared__ union {
        struct { float lw[64 * 65]; float lx[32 * 65]; } p1;  // 16.6 + 8.3 KB
        double ks[32 * 65];                                    // 16.6 KB
    } u;
    __shared__ double qs[32 * 65];                             // 16.6 KB
    int tid = threadIdx.x;
    int r0 = blockIdx.x * 32, bh = blockIdx.y;
    int b = bh >> 4, h = bh & 15;
    int isF = *flag;

    // ---- phase 1: exact Q rows r0..r0+31 of head h into qs (fp64) ----
    {
        int dk = tid & 63, rq = tid >> 6;    // rq in 0..3 -> rows rq*8..rq*8+7
        double acc8[8] = {};
        for (int kc = 0; kc < 16; ++kc) {
            __syncthreads();
            for (int i = tid; i < 64 * 64; i += 256) {
                int r = i >> 6, c = i & 63;
                u.p1.lw[r * 65 + c] = ldf_r9(Wq, (size_t)(h * 64 + r) * DD + kc * 64 + c, isF);
            }
            for (int i = tid; i < 32 * 64; i += 256) {
                int r = i >> 6, c = i & 63;
                u.p1.lx[r * 65 + c] = ldf_r9(query, ((size_t)b * LL + r0 + r) * DD + kc * 64 + c, isF);
            }
            __syncthreads();
#pragma unroll
            for (int a = 0; a < 8; ++a) {
                int row = rq * 8 + a;
                double s = 0;
                for (int c = 0; c < 64; ++c)
                    s += (double)u.p1.lx[row * 65 + c] * (double)u.p1.lw[dk * 65 + c];
                acc8[a] += s;
            }
        }
        double bb = (double)ldf_r9(bq, (size_t)(h * 64 + dk), isF);
#pragma unroll
        for (int a = 0; a < 8; ++a)
            qs[(rq * 8 + a) * 65 + dk] = acc8[a] + bb;
    }

    // ---- phase 2: max/sum over all 2048 keys, 2 rows x 2 keys per thread ----
    int g = tid >> 4, tx = tid & 15;   // rows g*2,g*2+1 ; keys tx, tx+16 per chunk
    double rmax0 = -1e300, rmax1 = -1e300;
    double rsum0 = 0.0, rsum1 = 0.0;
    for (int ch = 0; ch < 64; ++ch) {
        __syncthreads();   // qs writes (ch=0) / prior ks reads done
        for (int i = tid; i < 32 * 64; i += 256) {
            int r = i >> 6, d = i & 63;
            size_t o = ((size_t)bh * LL + ch * 32 + r) * DK + d;
            u.ks[r * 65 + d] = (double)Khi[o] + (double)Klo[o];
        }
        __syncthreads();
        double s00 = 0, s01 = 0, s10 = 0, s11 = 0;
        for (int d = 0; d < 64; ++d) {
            double k0 = u.ks[tx * 65 + d];
            double k1 = u.ks[(tx + 16) * 65 + d];
            double q0 = qs[(g * 2) * 65 + d];
            double q1 = qs[(g * 2 + 1) * 65 + d];
            s00 += q0 * k0; s01 += q0 * k1;
            s10 += q1 * k0; s11 += q1 * k1;
        }
        rmax0 = fmax(rmax0, fmax(s00, s01)); rsum0 += s00 + s01;
        rmax1 = fmax(rmax1, fmax(s10, s11)); rsum1 += s10 + s11;
    }
    // reduce across tx (lane bits 0..3 -> stays in-wave)
#pragma unroll
    for (int off = 1; off <= 8; off <<= 1) {
        rmax0 = fmax(rmax0, __shfl_xor(rmax0, off, 64));
        rmax1 = fmax(rmax1, __shfl_xor(rmax1, off, 64));
        rsum0 += __shfl_xor(rsum0, off, 64);
        rsum1 += __shfl_xor(rsum1, off, 64);
    }
    if (tx == 0) {
        Mv[(size_t)bh * LL + r0 + g * 2]     = rmax0 - rsum0 * (1.0 / 2048.0);
        Mv[(size_t)bh * LL + r0 + g * 2 + 1] = rmax1 - rsum1 * (1.0 / 2048.0);
    }
}

// ------- K4: exact top-40 per (b,h), DESCENDING (jax.lax.top_k), tie->low -------
__global__ __launch_bounds__(256) void topk_exact_r9(
    const double* __restrict__ Mv, int* __restrict__ sel)
{
    __shared__ double vals[LL];
    __shared__ double rv[256];
    __shared__ int ri[256];
    int bh = blockIdx.x, tid = threadIdx.x;
    for (int j = tid; j < LL; j += 256) vals[j] = Mv[(size_t)bh * LL + j];
    __syncthreads();
    for (int u = 0; u < UU; ++u) {
        double bv = -1e301; int bi = LL;
        for (int j = tid; j < LL; j += 256) {
            double v = vals[j];
            if (v > bv) { bv = v; bi = j; }
        }
        rv[tid] = bv; ri[tid] = bi;
        __syncthreads();
        for (int s = 128; s > 0; s >>= 1) {
            if (tid < s) {
                double ov = rv[tid + s]; int oi = ri[tid + s];
                if (ov > rv[tid] || (ov == rv[tid] && oi < ri[tid])) {
                    rv[tid] = ov; ri[tid] = oi;
                }
            }
            __syncthreads();
        }
        if (tid == 0) { sel[bh * UU + u] = ri[0]; vals[ri[0]] = -1e302; }
        __syncthreads();
    }
}

// ---- K5: exact q-row proj + scores + causal + softmax + probs + PV + attn ----
// OUTPUTS ARE FLOAT32 (reference output dtype is jnp.float32).
__global__ __launch_bounds__(256) void attn_out_r9(
    const void* __restrict__ query, const void* __restrict__ Wq,
    const void* __restrict__ bq, const float* __restrict__ Khi,
    const float* __restrict__ Klo, const float* __restrict__ Vf,
    const int* __restrict__ sel, float* __restrict__ attnOut,
    float* __restrict__ probsOut, const int* __restrict__ flag)
{
    __shared__ double qd[DK];
    __shared__ double redD[256];
    __shared__ float pl[LL];
    __shared__ float red[256];
    int u = blockIdx.x, bh = blockIdx.y, tid = threadIdx.x;
    int b = bh >> 4, h = bh & 15;
    int isF = *flag;
    int qpos = sel[bh * UU + u];

    {
        int dk = tid & 63, kg = tid >> 6;
        double s = 0;
        for (int k = kg * 256; k < kg * 256 + 256; ++k)
            s += (double)ldf_r9(query, ((size_t)b * LL + qpos) * DD + k, isF)
               * (double)ldf_r9(Wq, (size_t)(h * 64 + dk) * DD + k, isF);
        redD[tid] = s; __syncthreads();
        if (tid < 64) {
            double t = redD[tid] + redD[tid + 64] + redD[tid + 128] + redD[tid + 192];
            qd[tid] = t + (double)ldf_r9(bq, (size_t)(h * 64 + tid), isF);
        }
        __syncthreads();
    }

    float sloc[8];
    float lmax = -INFINITY;
#pragma unroll
    for (int c = 0; c < 8; ++c) {
        int l = c * 256 + tid;
        size_t o = ((size_t)bh * LL + l) * DK;
        double s = 0;
        for (int d = 0; d < 64; ++d)
            s += qd[d] * ((double)Khi[o + d] + (double)Klo[o + d]);
        float sf = (float)(s * 0.125);
        if (l > qpos) sf -= 1e9f;
        sloc[c] = sf;
        lmax = fmaxf(lmax, sf);
    }
    red[tid] = lmax; __syncthreads();
    for (int s2 = 128; s2 > 0; s2 >>= 1) {
        if (tid < s2) red[tid] = fmaxf(red[tid], red[tid + s2]);
        __syncthreads();
    }
    float mval = red[0];
    __syncthreads();
    float lsum = 0.f;
#pragma unroll
    for (int c = 0; c < 8; ++c) { sloc[c] = expf(sloc[c] - mval); lsum += sloc[c]; }
    red[tid] = lsum; __syncthreads();
    for (int s2 = 128; s2 > 0; s2 >>= 1) {
        if (tid < s2) red[tid] += red[tid + s2];
        __syncthreads();
    }
    float inv = 1.0f / red[0];
    size_t rowo = ((size_t)bh * UU + u) * LL;
#pragma unroll
    for (int c = 0; c < 8; ++c) {
        int l = c * 256 + tid;
        float p = sloc[c] * inv;
        pl[l] = p;
        probsOut[rowo + l] = p;           // fp32 store
    }
    __syncthreads();

    int dk = tid & 63, c4 = tid >> 6;
    const float* vb = Vf + (size_t)bh * LL * DK;
    float acc = 0.f;
    for (int l = c4 * (LL / 4); l < (c4 + 1) * (LL / 4); ++l)
        acc = fmaf(pl[l], vb[(size_t)l * DK + dk], acc);
    red[tid] = acc; __syncthreads();
    if (tid < 64) {
        float s2 = red[tid] + red[tid + 64] + red[tid + 128] + red[tid + 192];
        attnOut[((size_t)b * UU + u) * DD + h * DK + dk] = s2;   // fp32 store
    }
}

extern "C" void kernel_launch(void* const* d_in, const int* in_sizes, int n_in,
                              void* d_out, int out_size, void* d_ws, size_t ws_size,
                              hipStream_t stream) {
    (void)in_sizes; (void)n_in; (void)out_size; (void)ws_size;
    const void* query = d_in[0];
    const void* key   = d_in[1];
    const void* value = d_in[2];
    const void* Wq    = d_in[3];
    const void* bq    = d_in[4];
    const void* Wk    = d_in[5];
    const void* bk    = d_in[6];
    const void* Wv    = d_in[7];
    const void* bv    = d_in[8];

    char* w = (char*)d_ws;
    const size_t NE = (size_t)BB * HH * LL * DK;   // 4,194,304
    float* Khi = (float*)w;  w += NE * 4;
    float* Klo = (float*)w;  w += NE * 4;
    float* Vf  = (float*)w;  w += NE * 4;
    double* Mv = (double*)w; w += (size_t)BH * LL * 8;
    int* sel   = (int*)w;    w += (size_t)BH * UU * 4;
    int* flag  = (int*)w;    w += 64;
    // total ~50.9 MB (same as validated r8 layout)

    float* attnOut  = (float*)d_out;                       // FP32 outputs
    float* probsOut = attnOut + (size_t)BB * UU * DD;

    dim3 blk(256);
    detect_dtype_r9<<<1, blk, 0, stream>>>((const u16*)query, flag);
    kproj_exact_r9<<<dim3(64, 16), blk, 0, stream>>>(key, Wk, bk, Khi, Klo, flag);
    proj_v_r9<<<dim3(64, 16), blk, 0, stream>>>(value, Wv, bv, Vf, flag);
    qk_stats_r9<<<dim3(64, 32), blk, 0, stream>>>(query, Wq, bq, Khi, Klo, Mv, flag);
    topk_exact_r9<<<32, blk, 0, stream>>>(Mv, sel);
    attn_out_r9<<<dim3(UU, 32), blk, 0, stream>>>(query, Wq, bq, Khi, Klo, Vf,
                                                  sel, attnOut, probsOut, flag);
}